// Round 1
// baseline (373.825 us; speedup 1.0000x reference)
//
#include <hip/hip_runtime.h>

#define IMG_H 2048
#define IMG_W 4096
#define CH_ELEMS (IMG_H * IMG_W)        // 8388608 = 2^23
#define NUM_CH 6
#define SAMPLE_CH 3
#define HBINS 256
#define HIST_BPC 512                     // blocks per channel for histogram

// ---------------- Pass 1: per-channel histogram ----------------
__global__ __launch_bounds__(256) void eq_hist_kernel(
        const float* __restrict__ in, int* __restrict__ ghist) {
    __shared__ int lhist[4][HBINS];      // one sub-hist per wave (block = 4 waves)
    const int t = threadIdx.x;
    const int wave = t >> 6;
    for (int i = t; i < 4 * HBINS; i += 256) ((int*)lhist)[i] = 0;
    __syncthreads();

    const int ch  = blockIdx.x / HIST_BPC;
    const int blk = blockIdx.x % HIST_BPC;
    const float4* cin = (const float4*)(in + (size_t)ch * CH_ELEMS);
    const int n4 = CH_ELEMS / 4;         // 2097152

    for (int i = blk * 256 + t; i < n4; i += HIST_BPC * 256) {
        float4 v = cin[i];
        int bx = (int)v.x; bx = min(max(bx, 0), 255);
        int by = (int)v.y; by = min(max(by, 0), 255);
        int bz = (int)v.z; bz = min(max(bz, 0), 255);
        int bw = (int)v.w; bw = min(max(bw, 0), 255);
        atomicAdd(&lhist[wave][bx], 1);
        atomicAdd(&lhist[wave][by], 1);
        atomicAdd(&lhist[wave][bz], 1);
        atomicAdd(&lhist[wave][bw], 1);
    }
    __syncthreads();

    for (int i = t; i < HBINS; i += 256) {
        int s = lhist[0][i] + lhist[1][i] + lhist[2][i] + lhist[3][i];
        if (s) atomicAdd(&ghist[ch * HBINS + i], s);
    }
}

// ---------------- Pass 2: build LUTs (tiny) ----------------
__global__ void eq_lut_kernel(const int* __restrict__ ghist,
                              float* __restrict__ glut) {
    if (threadIdx.x != 0) return;
    const int ch = blockIdx.x;
    const int* hist = ghist + ch * HBINS;
    float* lut = glut + ch * HBINS;

    int total = 0, last_nz = 0;
    for (int i = 0; i < HBINS; i++) {
        int h = hist[i];
        total += h;
        if (h > 0) last_nz = i;
    }
    int step = (total - hist[last_nz]) / (HBINS - 1);
    if (step == 0) {
        // where(step==0, chan, ...) -> identity on the truncated int value
        for (int i = 0; i < HBINS; i++) lut[i] = (float)i;
        return;
    }
    lut[0] = 0.0f;                        // concat([0], lut[:-1])
    int cum = 0;
    const int half = step / 2;
    for (int i = 1; i < HBINS; i++) {
        cum += hist[i - 1];               // inclusive cumsum up to i-1
        int v = (cum + half) / step;
        v = min(max(v, 0), 255);
        lut[i] = (float)v;
    }
}

// ---------------- Pass 3: apply LUT + passthrough targets ----------------
__global__ __launch_bounds__(256) void eq_apply_kernel(
        const float* __restrict__ in, const float* __restrict__ glut,
        float* __restrict__ out) {
    __shared__ float slut[SAMPLE_CH * HBINS];
    for (int i = threadIdx.x; i < SAMPLE_CH * HBINS; i += 256)
        slut[i] = glut[i];
    __syncthreads();

    const float4* in4 = (const float4*)in;
    float4* out4 = (float4*)out;
    const int n4    = NUM_CH * CH_ELEMS / 4;   // 12582912
    const int ch_n4 = CH_ELEMS / 4;            // 2097152 = 2^21

    for (int i = blockIdx.x * 256 + threadIdx.x; i < n4; i += gridDim.x * 256) {
        float4 v = in4[i];
        const int ch = i / ch_n4;              // power-of-2 -> shift
        if (ch < SAMPLE_CH) {
            const float* l = slut + ch * HBINS;
            int bx = (int)v.x; bx = min(max(bx, 0), 255);
            int by = (int)v.y; by = min(max(by, 0), 255);
            int bz = (int)v.z; bz = min(max(bz, 0), 255);
            int bw = (int)v.w; bw = min(max(bw, 0), 255);
            v.x = l[bx]; v.y = l[by]; v.z = l[bz]; v.w = l[bw];
        }
        out4[i] = v;
    }
}

extern "C" void kernel_launch(void* const* d_in, const int* in_sizes, int n_in,
                              void* d_out, int out_size, void* d_ws, size_t ws_size,
                              hipStream_t stream) {
    const float* image = (const float*)d_in[0];
    float* out = (float*)d_out;

    int*   hist = (int*)d_ws;                          // 3*256 ints
    float* lut  = (float*)((char*)d_ws + SAMPLE_CH * HBINS * sizeof(int));

    // workspace is poisoned 0xAA every call — zero the histograms
    hipMemsetAsync(hist, 0, SAMPLE_CH * HBINS * sizeof(int), stream);

    eq_hist_kernel<<<SAMPLE_CH * HIST_BPC, 256, 0, stream>>>(image, hist);
    eq_lut_kernel<<<SAMPLE_CH, 64, 0, stream>>>(hist, lut);
    eq_apply_kernel<<<4096, 256, 0, stream>>>(image, lut, out);
}

// Round 2
// 368.675 us; speedup vs baseline: 1.0140x; 1.0140x over previous
//
#include <hip/hip_runtime.h>

#define IMG_H 2048
#define IMG_W 4096
#define CH_ELEMS (IMG_H * IMG_W)        // 8388608 = 2^23
#define CH_N4    (CH_ELEMS / 4)         // 2097152 = 2^21
#define NUM_CH 6
#define SAMPLE_CH 3
#define HBINS 256
#define BPC 512                          // blocks per channel, pass 1

// ws layout: [0, 1.5 MB) block-partial histograms (3*BPC*256 ints)
//            [2 MB, 2 MB + 3*256 floats) LUT
//            [4 MB, ...) packed u8 bins (3 * CH_ELEMS bytes = 25.2 MB)
#define WS_LUT_OFF  (2u << 20)
#define WS_U8_OFF   (4u << 20)

// ---------------- Pass 1: hist + u8 compress (sample) / copy (targets) -----
__global__ __launch_bounds__(256) void eq_pass1_kernel(
        const float* __restrict__ in, float* __restrict__ out,
        unsigned* __restrict__ u8buf, int* __restrict__ parts) {
    const int t   = threadIdx.x;
    const int ch  = blockIdx.x / BPC;
    const int blk = blockIdx.x % BPC;

    if (ch >= SAMPLE_CH) {
        // target channel: straight streaming copy, LUT-independent
        const float4* src = (const float4*)(in + (size_t)ch * CH_ELEMS);
        float4*       dst = (float4*)(out + (size_t)ch * CH_ELEMS);
        for (int i = blk * 256 + t; i < CH_N4; i += BPC * 256)
            dst[i] = src[i];
        return;
    }

    __shared__ int lh[4][HBINS];         // per-wave sub-hist
    const int wave = t >> 6;
    for (int i = t; i < 4 * HBINS; i += 256) ((int*)lh)[i] = 0;
    __syncthreads();

    const float4* src = (const float4*)(in + (size_t)ch * CH_ELEMS);
    unsigned*     dst = u8buf + ch * CH_N4;

    for (int i = blk * 256 + t; i < CH_N4; i += BPC * 256) {
        float4 v = src[i];
        int b0 = (int)v.x; b0 = min(max(b0, 0), 255);
        int b1 = (int)v.y; b1 = min(max(b1, 0), 255);
        int b2 = (int)v.z; b2 = min(max(b2, 0), 255);
        int b3 = (int)v.w; b3 = min(max(b3, 0), 255);
        atomicAdd(&lh[wave][b0], 1);
        atomicAdd(&lh[wave][b1], 1);
        atomicAdd(&lh[wave][b2], 1);
        atomicAdd(&lh[wave][b3], 1);
        dst[i] = (unsigned)b0 | ((unsigned)b1 << 8) |
                 ((unsigned)b2 << 16) | ((unsigned)b3 << 24);
    }
    __syncthreads();

    // plain store of this block's complete partial hist — no pre-zero needed
    parts[((size_t)ch * BPC + blk) * HBINS + t] =
        lh[0][t] + lh[1][t] + lh[2][t] + lh[3][t];
}

// ---------------- Pass 2: build LUTs (3 blocks x 256 threads) --------------
__global__ __launch_bounds__(256) void eq_lut_kernel(
        const int* __restrict__ parts, float* __restrict__ glut) {
    const int ch = blockIdx.x;
    const int t  = threadIdx.x;
    const int* p = parts + (size_t)ch * BPC * HBINS;

    int h = 0;
    #pragma unroll 8
    for (int j = 0; j < BPC; j++) h += p[j * HBINS + t];   // coalesced across t

    __shared__ int sh[HBINS];   // original hist
    __shared__ int sc[HBINS];   // inclusive cumsum
    __shared__ int nz[HBINS];   // last-nonzero reduction
    sh[t] = h;
    sc[t] = h;
    nz[t] = (h > 0) ? t : 0;
    __syncthreads();

    // Hillis-Steele inclusive scan
    for (int off = 1; off < HBINS; off <<= 1) {
        int add = (t >= off) ? sc[t - off] : 0;
        __syncthreads();
        sc[t] += add;
        __syncthreads();
    }
    // max-reduce for last nonzero bin
    for (int off = HBINS / 2; off >= 1; off >>= 1) {
        if (t < off) nz[t] = max(nz[t], nz[t + off]);
        __syncthreads();
    }

    const int total   = sc[HBINS - 1];
    const int last_nz = nz[0];
    const int step    = (total - sh[last_nz]) / (HBINS - 1);  // all >=0: trunc==floor

    float outv;
    if (step == 0) {
        outv = (float)t;                 // where(step==0, chan, ...)
    } else if (t == 0) {
        outv = 0.0f;                     // concat([0], lut[:-1]) then clip
    } else {
        int v = (sc[t - 1] + (step >> 1)) / step;
        outv = (float)min(v, 255);       // v >= 0 always
    }
    glut[ch * HBINS + t] = outv;
}

// ---------------- Pass 3: apply LUT to u8 bins -----------------------------
__global__ __launch_bounds__(256) void eq_apply_kernel(
        const unsigned* __restrict__ u8buf, const float* __restrict__ glut,
        float* __restrict__ out) {
    __shared__ float sl[SAMPLE_CH * HBINS];
    for (int i = threadIdx.x; i < SAMPLE_CH * HBINS; i += 256)
        sl[i] = glut[i];
    __syncthreads();

    float4* out4 = (float4*)out;
    const int n = SAMPLE_CH * CH_N4;     // 6291456

    for (int i = blockIdx.x * 256 + threadIdx.x; i < n; i += gridDim.x * 256) {
        unsigned w = u8buf[i];
        const float* l = sl + (i >> 21) * HBINS;   // i / CH_N4
        float4 o;
        o.x = l[w & 255u];
        o.y = l[(w >> 8) & 255u];
        o.z = l[(w >> 16) & 255u];
        o.w = l[w >> 24];
        out4[i] = o;
    }
}

extern "C" void kernel_launch(void* const* d_in, const int* in_sizes, int n_in,
                              void* d_out, int out_size, void* d_ws, size_t ws_size,
                              hipStream_t stream) {
    const float* image = (const float*)d_in[0];
    float* out = (float*)d_out;

    int*      parts = (int*)d_ws;
    float*    lut   = (float*)((char*)d_ws + WS_LUT_OFF);
    unsigned* u8buf = (unsigned*)((char*)d_ws + WS_U8_OFF);

    eq_pass1_kernel<<<NUM_CH * BPC, 256, 0, stream>>>(image, out, u8buf, parts);
    eq_lut_kernel<<<SAMPLE_CH, 256, 0, stream>>>(parts, lut);
    eq_apply_kernel<<<2048, 256, 0, stream>>>(u8buf, lut, out);
}